// Round 1
// baseline (633.097 us; speedup 1.0000x reference)
//
#include <hip/hip_runtime.h>
#include <math.h>

#define NN 4096      // nodes = B*S
#define D 256        // DIN == DOUT
#define RR 8
#define LL 4
#define EE 65536
#define BB 8
#define SS 512
#define HH 8
#define DEPTH 32

// ---------------- generic fp32 tiled GEMM ----------------
// C[M,Nc] = A[M,K] * B(+bias). BT=true: B is [Nc,K] row-major (use B^T).
// BT=false: B is [K,Nc] row-major. blockIdx.z strides B by K*Nc and C by M*Nc.
template<bool BT>
__global__ __launch_bounds__(256) void gemm_f32(const float* __restrict__ A,
    const float* __restrict__ B, const float* __restrict__ bias,
    float* __restrict__ C, int M, int Nc, int K)
{
  __shared__ float As[16][65];
  __shared__ float Bs[16][65];
  int tid = threadIdx.x;
  int rb = blockIdx.y * 64;
  int cb = blockIdx.x * 64;
  const float* Bp = B + (size_t)blockIdx.z * ((size_t)K * Nc);
  float* Cp = C + (size_t)blockIdx.z * ((size_t)M * Nc);
  float acc[4][4] = {};
  int tr = tid >> 4, tc = tid & 15;
  int la_i = tid >> 2;           // 0..63
  int la_k = (tid & 3) * 4;      // 0,4,8,12

  for (int k0 = 0; k0 < K; k0 += 16) {
    float4 av = *(const float4*)(A + (size_t)(rb + la_i) * K + k0 + la_k);
    As[la_k+0][la_i] = av.x; As[la_k+1][la_i] = av.y;
    As[la_k+2][la_i] = av.z; As[la_k+3][la_i] = av.w;
    if (BT) {
      float4 bv = *(const float4*)(Bp + (size_t)(cb + la_i) * K + k0 + la_k);
      Bs[la_k+0][la_i] = bv.x; Bs[la_k+1][la_i] = bv.y;
      Bs[la_k+2][la_i] = bv.z; Bs[la_k+3][la_i] = bv.w;
    } else {
      int lb_k = tid >> 4;           // 0..15
      int lb_j = (tid & 15) * 4;     // 0..60
      float4 bv = *(const float4*)(Bp + (size_t)(k0 + lb_k) * Nc + cb + lb_j);
      Bs[lb_k][lb_j+0] = bv.x; Bs[lb_k][lb_j+1] = bv.y;
      Bs[lb_k][lb_j+2] = bv.z; Bs[lb_k][lb_j+3] = bv.w;
    }
    __syncthreads();
#pragma unroll
    for (int kk = 0; kk < 16; ++kk) {
      float a0 = As[kk][tr], a1 = As[kk][tr+16], a2 = As[kk][tr+32], a3 = As[kk][tr+48];
      float b0 = Bs[kk][tc], b1 = Bs[kk][tc+16], b2 = Bs[kk][tc+32], b3 = Bs[kk][tc+48];
      acc[0][0] += a0*b0; acc[0][1] += a0*b1; acc[0][2] += a0*b2; acc[0][3] += a0*b3;
      acc[1][0] += a1*b0; acc[1][1] += a1*b1; acc[1][2] += a1*b2; acc[1][3] += a1*b3;
      acc[2][0] += a2*b0; acc[2][1] += a2*b1; acc[2][2] += a2*b2; acc[2][3] += a2*b3;
      acc[3][0] += a3*b0; acc[3][1] += a3*b1; acc[3][2] += a3*b2; acc[3][3] += a3*b3;
    }
    __syncthreads();
  }
#pragma unroll
  for (int u = 0; u < 4; ++u) {
#pragma unroll
    for (int v = 0; v < 4; ++v) {
      int r_ = rb + tr + 16*u, c_ = cb + tc + 16*v;
      float val = acc[u][v];
      if (bias) val += bias[c_];
      Cp[(size_t)r_ * Nc + c_] = val;
    }
  }
}

// ---------------- CSR build ----------------
__global__ void count_k(const int* __restrict__ ed, int* __restrict__ cnt) {
  int e = blockIdx.x * 256 + threadIdx.x;
  if (e < EE) atomicAdd(&cnt[ed[e]], 1);
}

__global__ __launch_bounds__(1024) void scan_k(const int* __restrict__ cnt,
    int* __restrict__ off, int* __restrict__ cur) {
  __shared__ int part[1024];
  int t = threadIdx.x;
  int base = t * 4;
  int c0 = cnt[base], c1 = cnt[base+1], c2 = cnt[base+2], c3 = cnt[base+3];
  int s = c0 + c1 + c2 + c3;
  part[t] = s;
  __syncthreads();
  for (int o = 1; o < 1024; o <<= 1) {
    int v = 0;
    if (t >= o) v = part[t - o];
    __syncthreads();
    part[t] += v;
    __syncthreads();
  }
  int excl = part[t] - s;
  int o0 = excl, o1 = excl + c0, o2 = excl + c0 + c1, o3 = excl + c0 + c1 + c2;
  off[base] = o0; off[base+1] = o1; off[base+2] = o2; off[base+3] = o3;
  cur[base] = o0; cur[base+1] = o1; cur[base+2] = o2; cur[base+3] = o3;
  if (t == 1023) off[NN] = EE;
}

__global__ void fill_k(const int* __restrict__ ed, int* __restrict__ cur,
                       int* __restrict__ csr) {
  int e = blockIdx.x * 256 + threadIdx.x;
  if (e < EE) { int p = atomicAdd(&cur[ed[e]], 1); csr[p] = e; }
}

// ---------------- per-(r,n) attention score dots ----------------
__global__ __launch_bounds__(256) void scores_k(const float* __restrict__ hr,
    const float* __restrict__ h, const float* __restrict__ a_src_l,
    const float* __restrict__ a_dst_l, float* __restrict__ ssrc,
    float* __restrict__ sdst)
{
  int wave = threadIdx.x >> 6;
  int lane = threadIdx.x & 63;
  int idx = blockIdx.x * 4 + wave;   // r*NN + n
  int r = idx >> 12;
  int n = idx & (NN - 1);
  const float* hrp = hr + ((size_t)r * NN + n) * D;
  const float* asp = a_src_l + r * D;
  const float* adp = a_dst_l + r * D;
  const float* hp = h + (size_t)n * D;
  float s1 = 0.f, s2 = 0.f;
  for (int i = lane; i < D; i += 64) { s1 += hrp[i] * asp[i]; s2 += hp[i] * adp[i]; }
#pragma unroll
  for (int o = 32; o; o >>= 1) { s1 += __shfl_down(s1, o); s2 += __shfl_down(s2, o); }
  if (lane == 0) { ssrc[idx] = s1; sdst[idx] = s2; }
}

// ---------------- per-edge logits (leaky relu) ----------------
__global__ void edge_logits_k(const int* __restrict__ et, const int* __restrict__ es,
    const int* __restrict__ ed, const float* __restrict__ ssrc,
    const float* __restrict__ sdst, float* __restrict__ logit)
{
  int e = blockIdx.x * 256 + threadIdx.x;
  if (e >= EE) return;
  int t = et[e];
  float v = ssrc[t * NN + es[e]] + sdst[t * NN + ed[e]];
  logit[e] = v > 0.f ? v : 0.2f * v;
}

// ---------------- per-node softmax stats ----------------
__global__ __launch_bounds__(256) void node_softmax_k(const int* __restrict__ csr,
    const int* __restrict__ off, const float* __restrict__ logit,
    float* __restrict__ mx, float* __restrict__ dn)
{
  int wave = threadIdx.x >> 6, lane = threadIdx.x & 63;
  int n = blockIdx.x * 4 + wave;
  int o0 = off[n], o1 = off[n + 1];
  float m = -INFINITY;
  for (int i = o0 + lane; i < o1; i += 64) m = fmaxf(m, logit[csr[i]]);
#pragma unroll
  for (int o = 32; o; o >>= 1) m = fmaxf(m, __shfl_xor(m, o));
  float s = 0.f;
  for (int i = o0 + lane; i < o1; i += 64) s += expf(logit[csr[i]] - m);
#pragma unroll
  for (int o = 32; o; o >>= 1) s += __shfl_xor(s, o);
  if (lane == 0) { mx[n] = m; dn[n] = s; }
}

// ---------------- per-node aggregation + ELU (writes h in place) ----------------
__global__ __launch_bounds__(256) void agg_k(const int* __restrict__ csr,
    const int* __restrict__ off, const int* __restrict__ et,
    const int* __restrict__ es, const float* __restrict__ logit,
    const float* __restrict__ mx, const float* __restrict__ dn,
    const float* __restrict__ hr, float* __restrict__ hout)
{
  int n = blockIdx.x;
  int o0 = off[n], o1 = off[n + 1];
  float m = mx[n];
  float dinv = 1.0f / (dn[n] + 1e-16f);
  int ch = threadIdx.x;
  float acc = 0.f;
  for (int i = o0; i < o1; ++i) {
    int e = csr[i];
    float w = expf(logit[e] - m) * dinv;
    const float* row = hr + ((size_t)et[e] * NN + es[e]) * D;
    acc += w * row[ch];
  }
  hout[(size_t)n * D + ch] = acc > 0.f ? acc : expm1f(acc);
}

// ---------------- final attention scores ----------------
__global__ __launch_bounds__(256) void attn_k(const float* __restrict__ q,
    const float* __restrict__ kmat, float* __restrict__ out)
{
  __shared__ float Qs[64][36];
  __shared__ float Kst[32][68];
  int tid = threadIdx.x;
  int bh = blockIdx.y; int b = bh >> 3, h = bh & 7;
  int rb = (blockIdx.x >> 3) * 64, cb = (blockIdx.x & 7) * 64;
  int li = tid >> 2, ld = (tid & 3) * 8;

  const float* qp = q + ((size_t)(b * SS) + rb + li) * D + h * DEPTH + ld;
  const float* kp = kmat + ((size_t)(b * SS) + cb + li) * D + h * DEPTH + ld;
  float4 q0 = *(const float4*)qp, q1 = *(const float4*)(qp + 4);
  float4 k0 = *(const float4*)kp, k1 = *(const float4*)(kp + 4);
  *(float4*)&Qs[li][ld] = q0; *(float4*)&Qs[li][ld + 4] = q1;
  Kst[ld+0][li] = k0.x; Kst[ld+1][li] = k0.y; Kst[ld+2][li] = k0.z; Kst[ld+3][li] = k0.w;
  Kst[ld+4][li] = k1.x; Kst[ld+5][li] = k1.y; Kst[ld+6][li] = k1.z; Kst[ld+7][li] = k1.w;
  __syncthreads();

  int tr = tid >> 4, tc = tid & 15;
  float acc[4][4] = {};
#pragma unroll
  for (int d = 0; d < 32; ++d) {
    float a0 = Qs[tr][d], a1 = Qs[tr+16][d], a2 = Qs[tr+32][d], a3 = Qs[tr+48][d];
    float b0 = Kst[d][tc*4+0], b1 = Kst[d][tc*4+1], b2 = Kst[d][tc*4+2], b3 = Kst[d][tc*4+3];
    acc[0][0] += a0*b0; acc[0][1] += a0*b1; acc[0][2] += a0*b2; acc[0][3] += a0*b3;
    acc[1][0] += a1*b0; acc[1][1] += a1*b1; acc[1][2] += a1*b2; acc[1][3] += a1*b3;
    acc[2][0] += a2*b0; acc[2][1] += a2*b1; acc[2][2] += a2*b2; acc[2][3] += a2*b3;
    acc[3][0] += a3*b0; acc[3][1] += a3*b1; acc[3][2] += a3*b2; acc[3][3] += a3*b3;
  }
  const float scale = 0.17677669529663687f; // 1/sqrt(32)
  size_t ob = (size_t)bh * SS * SS;
#pragma unroll
  for (int u = 0; u < 4; ++u) {
    float4 v = make_float4(acc[u][0]*scale, acc[u][1]*scale, acc[u][2]*scale, acc[u][3]*scale);
    *(float4*)(out + ob + (size_t)(rb + tr + 16*u) * SS + cb + tc*4) = v;
  }
}

// ---------------- launcher ----------------
extern "C" void kernel_launch(void* const* d_in, const int* in_sizes, int n_in,
                              void* d_out, int out_size, void* d_ws, size_t ws_size,
                              hipStream_t stream) {
  const float* x    = (const float*)d_in[0];
  const int*   es   = (const int*)d_in[1];
  const int*   ed   = (const int*)d_in[2];
  const int*   et   = (const int*)d_in[3];
  const float* Wl   = (const float*)d_in[4];
  const float* bl   = (const float*)d_in[5];
  const float* Wgat = (const float*)d_in[6];
  const float* asr  = (const float*)d_in[7];
  const float* adt  = (const float*)d_in[8];
  const float* W1   = (const float*)d_in[9];
  const float* b1   = (const float*)d_in[10];
  const float* Wq   = (const float*)d_in[11];
  const float* bq   = (const float*)d_in[12];
  const float* Wk   = (const float*)d_in[13];
  const float* bk   = (const float*)d_in[14];
  float* out = (float*)d_out;

  char* w = (char*)d_ws;
  size_t o = 0;
  auto alloc = [&](size_t bytes) { void* p = w + o; o += (bytes + 255) & ~(size_t)255; return p; };
  float* h    = (float*)alloc((size_t)NN * D * 4);
  float* hr   = (float*)alloc((size_t)RR * NN * D * 4);
  float* h1   = (float*)alloc((size_t)NN * D * 4);
  float* q    = (float*)alloc((size_t)NN * D * 4);
  float* kbuf = (float*)alloc((size_t)NN * D * 4);
  float* ssrc = (float*)alloc((size_t)RR * NN * 4);
  float* sdst = (float*)alloc((size_t)RR * NN * 4);
  float* logit= (float*)alloc((size_t)EE * 4);
  float* mx   = (float*)alloc((size_t)NN * 4);
  float* dn   = (float*)alloc((size_t)NN * 4);
  int*   cnt  = (int*)alloc((size_t)NN * 4);
  int*   off  = (int*)alloc((size_t)(NN + 1) * 4);
  int*   cur  = (int*)alloc((size_t)NN * 4);
  int*   csr  = (int*)alloc((size_t)EE * 4);

  // CSR build (edge list is a constant input; rebuilt every call for determinism)
  hipMemsetAsync(cnt, 0, NN * sizeof(int), stream);
  count_k<<<EE / 256, 256, 0, stream>>>(ed, cnt);
  scan_k<<<1, 1024, 0, stream>>>(cnt, off, cur);
  fill_k<<<EE / 256, 256, 0, stream>>>(ed, cur, csr);

  // h = x @ Wl^T + bl
  gemm_f32<true><<<dim3(4, 64, 1), 256, 0, stream>>>(x, Wl, bl, h, NN, D, D);

  for (int l = 0; l < LL; ++l) {
    // hr[r] = h @ Wgat[l,r]  (B is [D,D] row-major: k=d, n=e)
    gemm_f32<false><<<dim3(4, 64, RR), 256, 0, stream>>>(
        h, Wgat + (size_t)l * RR * D * D, nullptr, hr, NN, D, D);
    scores_k<<<RR * NN / 4, 256, 0, stream>>>(
        hr, h, asr + (size_t)l * RR * D, adt + (size_t)l * RR * D, ssrc, sdst);
    edge_logits_k<<<EE / 256, 256, 0, stream>>>(et, es, ed, ssrc, sdst, logit);
    node_softmax_k<<<NN / 4, 256, 0, stream>>>(csr, off, logit, mx, dn);
    agg_k<<<NN, 256, 0, stream>>>(csr, off, et, es, logit, mx, dn, hr, h);
  }

  // h1 = h @ W1^T + b1 ; q = h1 @ Wq^T + bq ; k = h1 @ Wk^T + bk
  gemm_f32<true><<<dim3(4, 64, 1), 256, 0, stream>>>(h, W1, b1, h1, NN, D, D);
  gemm_f32<true><<<dim3(4, 64, 1), 256, 0, stream>>>(h1, Wq, bq, q, NN, D, D);
  gemm_f32<true><<<dim3(4, 64, 1), 256, 0, stream>>>(h1, Wk, bk, kbuf, NN, D, D);

  attn_k<<<dim3(64, BB * HH), 256, 0, stream>>>(q, kbuf, out);
}

// Round 2
// 392.656 us; speedup vs baseline: 1.6123x; 1.6123x over previous
//
#include <hip/hip_runtime.h>
#include <math.h>

#define NN 4096      // nodes = B*S
#define D 256        // DIN == DOUT
#define RR 8
#define LL 4
#define EE 65536
#define BB 8
#define SS 512
#define HH 8

typedef short bf16x8 __attribute__((ext_vector_type(8)));
typedef float f32x4 __attribute__((ext_vector_type(4)));

__device__ __forceinline__ unsigned short f2bf(float f) {
  unsigned u = __float_as_uint(f);
  unsigned r = (u + 0x7fffu + ((u >> 16) & 1u)) >> 16;
  return (unsigned short)r;
}
__device__ __forceinline__ float bf2f(unsigned short s) {
  return __uint_as_float(((unsigned)s) << 16);
}

__device__ __forceinline__ void gload16(unsigned short* dst, const unsigned short* src) {
  __builtin_amdgcn_global_load_lds(
      (const __attribute__((address_space(1))) void*)src,
      (__attribute__((address_space(3))) void*)dst, 16, 0, 0);
}

// ---------------- split-bf16 MFMA GEMM ----------------
// C[M,N] = (Ah+Al)[M,K] * (Bh+Bl)[N,K]^T (+bias), fp32 accum.
// 3-term split: Ah*Bh + Al*Bh + Ah*Bl. 256 threads = 4 waves in 2x2 grid.
template<int BM, int BN, bool F32OUT, bool SPLITOUT>
__global__ __launch_bounds__(256) void gemm_split(
    const unsigned short* __restrict__ Ah, const unsigned short* __restrict__ Al,
    const unsigned short* __restrict__ Bh, const unsigned short* __restrict__ Bl,
    const float* __restrict__ bias,
    float* __restrict__ C, unsigned short* __restrict__ Ch, unsigned short* __restrict__ Cl,
    int M, int N, int K)
{
  constexpr int MF = BM / 32;   // 16x16 frags per wave (m)
  constexpr int NF = BN / 32;
  __shared__ unsigned short lds[2 * (BM + BN) * 32];
  unsigned short* lA = lds;                 // [Ah: BM*32][Al: BM*32]
  unsigned short* lB = lds + 2 * BM * 32;   // [Bh: BN*32][Bl: BN*32]

  const int t = threadIdx.x;
  const int lane = t & 63;
  const int w = t >> 6;
  const int wm = w >> 1, wn = w & 1;
  const int rb = blockIdx.y * BM;
  const int cb = blockIdx.x * BN;

  f32x4 acc[MF][NF];
#pragma unroll
  for (int m = 0; m < MF; ++m)
#pragma unroll
    for (int n = 0; n < NF; ++n)
      acc[m][n] = (f32x4){0.f, 0.f, 0.f, 0.f};

  const int srow = t >> 2, sslot = t & 3;
  const unsigned short* gAh = Ah + (size_t)(rb + srow) * K + sslot * 8;
  const unsigned short* gAl = Al + (size_t)(rb + srow) * K + sslot * 8;
  const unsigned short* gBh = Bh + (size_t)(cb + srow) * K + sslot * 8;
  const unsigned short* gBl = Bl + (size_t)(cb + srow) * K + sslot * 8;

  for (int k0 = 0; k0 < K; k0 += 32) {
#pragma unroll
    for (int i = 0; i < BM / 64; ++i) {
      gload16(lA + i * 2048 + t * 8,           gAh + (size_t)i * 64 * K + k0);
      gload16(lA + BM * 32 + i * 2048 + t * 8, gAl + (size_t)i * 64 * K + k0);
    }
#pragma unroll
    for (int i = 0; i < BN / 64; ++i) {
      gload16(lB + i * 2048 + t * 8,           gBh + (size_t)i * 64 * K + k0);
      gload16(lB + BN * 32 + i * 2048 + t * 8, gBl + (size_t)i * 64 * K + k0);
    }
    __syncthreads();

    bf16x8 ah[MF], al[MF];
#pragma unroll
    for (int m = 0; m < MF; ++m) {
      int off = (wm * (BM / 2) + m * 16 + (lane & 15)) * 32 + (lane >> 4) * 8;
      ah[m] = *(const bf16x8*)(lA + off);
      al[m] = *(const bf16x8*)(lA + BM * 32 + off);
    }
#pragma unroll
    for (int n = 0; n < NF; ++n) {
      int boff = (wn * (BN / 2) + n * 16 + (lane & 15)) * 32 + (lane >> 4) * 8;
      bf16x8 bh = *(const bf16x8*)(lB + boff);
      bf16x8 bl = *(const bf16x8*)(lB + BN * 32 + boff);
#pragma unroll
      for (int m = 0; m < MF; ++m) {
        acc[m][n] = __builtin_amdgcn_mfma_f32_16x16x32_bf16(ah[m], bh, acc[m][n], 0, 0, 0);
        acc[m][n] = __builtin_amdgcn_mfma_f32_16x16x32_bf16(al[m], bh, acc[m][n], 0, 0, 0);
        acc[m][n] = __builtin_amdgcn_mfma_f32_16x16x32_bf16(ah[m], bl, acc[m][n], 0, 0, 0);
      }
    }
    __syncthreads();
  }

#pragma unroll
  for (int m = 0; m < MF; ++m) {
#pragma unroll
    for (int n = 0; n < NF; ++n) {
      int row0 = rb + wm * (BM / 2) + m * 16 + (lane >> 4) * 4;
      int col = cb + wn * (BN / 2) + n * 16 + (lane & 15);
      float bv = bias ? bias[col] : 0.f;
#pragma unroll
      for (int j = 0; j < 4; ++j) {
        float v = acc[m][n][j] + bv;
        size_t idx = (size_t)(row0 + j) * N + col;
        if (F32OUT) C[idx] = v;
        if (SPLITOUT) {
          unsigned short hb = f2bf(v);
          Ch[idx] = hb;
          Cl[idx] = f2bf(v - bf2f(hb));
        }
      }
    }
  }
}

// ---------------- fp32 -> bf16 hi/lo split ----------------
__global__ __launch_bounds__(256) void cvt_split_k(const float* __restrict__ src,
    unsigned short* __restrict__ hi, unsigned short* __restrict__ lo, int n4)
{
  int i = blockIdx.x * 256 + threadIdx.x;
  if (i >= n4) return;
  float4 v = ((const float4*)src)[i];
  ushort4 h, l;
  h.x = f2bf(v.x); l.x = f2bf(v.x - bf2f(h.x));
  h.y = f2bf(v.y); l.y = f2bf(v.y - bf2f(h.y));
  h.z = f2bf(v.z); l.z = f2bf(v.z - bf2f(h.z));
  h.w = f2bf(v.w); l.w = f2bf(v.w - bf2f(h.w));
  ((ushort4*)hi)[i] = h;
  ((ushort4*)lo)[i] = l;
}

// ---------------- Wgat [G][D][D] -> transposed hi/lo [G][D][D] (e-major) ---------
__global__ __launch_bounds__(256) void transp_split_k(const float* __restrict__ W,
    unsigned short* __restrict__ th, unsigned short* __restrict__ tl)
{
  __shared__ float s[32][33];
  int g = blockIdx.z, bi = blockIdx.y, bj = blockIdx.x;
  int t = threadIdx.x;
  int r = t >> 3, c = (t & 7) * 4;
  float4 v = *(const float4*)(W + ((size_t)g * D + bi * 32 + r) * D + bj * 32 + c);
  s[r][c + 0] = v.x; s[r][c + 1] = v.y; s[r][c + 2] = v.z; s[r][c + 3] = v.w;
  __syncthreads();
  size_t ob = ((size_t)g * D + bj * 32 + r) * D + bi * 32 + c;
  ushort4 h, l;
  float o0 = s[c + 0][r], o1 = s[c + 1][r], o2 = s[c + 2][r], o3 = s[c + 3][r];
  h.x = f2bf(o0); l.x = f2bf(o0 - bf2f(h.x));
  h.y = f2bf(o1); l.y = f2bf(o1 - bf2f(h.y));
  h.z = f2bf(o2); l.z = f2bf(o2 - bf2f(h.z));
  h.w = f2bf(o3); l.w = f2bf(o3 - bf2f(h.w));
  *(ushort4*)(th + ob) = h;
  *(ushort4*)(tl + ob) = l;
}

// ---------------- CSR build ----------------
__global__ void count_k(const int* __restrict__ ed, int* __restrict__ cnt) {
  int e = blockIdx.x * 256 + threadIdx.x;
  if (e < EE) atomicAdd(&cnt[ed[e]], 1);
}

__global__ __launch_bounds__(1024) void scan_k(const int* __restrict__ cnt,
    int* __restrict__ off, int* __restrict__ cur) {
  __shared__ int part[1024];
  int t = threadIdx.x;
  int base = t * 4;
  int c0 = cnt[base], c1 = cnt[base+1], c2 = cnt[base+2], c3 = cnt[base+3];
  int s = c0 + c1 + c2 + c3;
  part[t] = s;
  __syncthreads();
  for (int o = 1; o < 1024; o <<= 1) {
    int v = 0;
    if (t >= o) v = part[t - o];
    __syncthreads();
    part[t] += v;
    __syncthreads();
  }
  int excl = part[t] - s;
  off[base] = excl; off[base+1] = excl + c0; off[base+2] = excl + c0 + c1;
  off[base+3] = excl + c0 + c1 + c2;
  cur[base] = excl; cur[base+1] = excl + c0; cur[base+2] = excl + c0 + c1;
  cur[base+3] = excl + c0 + c1 + c2;
  if (t == 1023) off[NN] = EE;
}

__global__ void fill_k(const int* __restrict__ ed, int* __restrict__ cur,
                       int* __restrict__ csr) {
  int e = blockIdx.x * 256 + threadIdx.x;
  if (e < EE) { int p = atomicAdd(&cur[ed[e]], 1); csr[p] = e; }
}

// ---------------- wa[r] = Wgat[l,r] @ a_src[l,r]  (fp32) ----------------
__global__ __launch_bounds__(256) void wa_k(const float* __restrict__ Wg,
    const float* __restrict__ asrc, float* __restrict__ wa)
{
  int wid = blockIdx.x * 4 + (threadIdx.x >> 6);   // 0..R*D-1
  int lane = threadIdx.x & 63;
  int r = wid >> 8, d = wid & 255;
  const float* row = Wg + ((size_t)r * D + d) * D;
  const float* av = asrc + (size_t)r * D;
  float s = 0.f;
  for (int i = lane; i < D; i += 64) s += row[i] * av[i];
#pragma unroll
  for (int o = 32; o; o >>= 1) s += __shfl_down(s, o);
  if (lane == 0) wa[r * D + d] = s;
}

// ---------------- ssrc[r,n]=h[n].wa[r], sdst[r,n]=h[n].a_dst[r] ----------------
__global__ __launch_bounds__(256) void scores2_k(const float* __restrict__ h,
    const float* __restrict__ wa, const float* __restrict__ adst,
    float* __restrict__ ssrc, float* __restrict__ sdst)
{
  int n = blockIdx.x;
  int w = threadIdx.x >> 6, lane = threadIdx.x & 63;
  float4 hv = ((const float4*)(h + (size_t)n * D))[lane];
#pragma unroll
  for (int rr = 0; rr < 2; ++rr) {
    int r = w * 2 + rr;
    float4 a = ((const float4*)(wa + (size_t)r * D))[lane];
    float4 b = ((const float4*)(adst + (size_t)r * D))[lane];
    float s1 = hv.x*a.x + hv.y*a.y + hv.z*a.z + hv.w*a.w;
    float s2 = hv.x*b.x + hv.y*b.y + hv.z*b.z + hv.w*b.w;
#pragma unroll
    for (int o = 32; o; o >>= 1) { s1 += __shfl_down(s1, o); s2 += __shfl_down(s2, o); }
    if (lane == 0) { ssrc[(size_t)r * NN + n] = s1; sdst[(size_t)r * NN + n] = s2; }
  }
}

// ---------------- per-edge logits (leaky relu) ----------------
__global__ void edge_logits_k(const int* __restrict__ et, const int* __restrict__ es,
    const int* __restrict__ ed, const float* __restrict__ ssrc,
    const float* __restrict__ sdst, float* __restrict__ logit)
{
  int e = blockIdx.x * 256 + threadIdx.x;
  if (e >= EE) return;
  int t = et[e];
  float v = ssrc[(size_t)t * NN + es[e]] + sdst[(size_t)t * NN + ed[e]];
  logit[e] = v > 0.f ? v : 0.2f * v;
}

// ---------------- per-node softmax stats ----------------
__global__ __launch_bounds__(256) void node_softmax_k(const int* __restrict__ csr,
    const int* __restrict__ off, const float* __restrict__ logit,
    float* __restrict__ mx, float* __restrict__ dn)
{
  int wave = threadIdx.x >> 6, lane = threadIdx.x & 63;
  int n = blockIdx.x * 4 + wave;
  int o0 = off[n], o1 = off[n + 1];
  float m = -INFINITY;
  for (int i = o0 + lane; i < o1; i += 64) m = fmaxf(m, logit[csr[i]]);
#pragma unroll
  for (int o = 32; o; o >>= 1) m = fmaxf(m, __shfl_xor(m, o));
  float s = 0.f;
  for (int i = o0 + lane; i < o1; i += 64) s += expf(logit[csr[i]] - m);
#pragma unroll
  for (int o = 32; o; o >>= 1) s += __shfl_xor(s, o);
  if (lane == 0) { mx[n] = m; dn[n] = s; }
}

// ---------------- per-edge alpha ----------------
__global__ void alpha_k(const int* __restrict__ ed, const float* __restrict__ logit,
    const float* __restrict__ mx, const float* __restrict__ dn,
    float* __restrict__ alpha)
{
  int e = blockIdx.x * 256 + threadIdx.x;
  if (e >= EE) return;
  int n = ed[e];
  alpha[e] = expf(logit[e] - mx[n]) / (dn[n] + 1e-16f);
}

// --------- per-node aggregation + ELU -> h fp32 + bf16 hi/lo split ---------
__global__ __launch_bounds__(256) void agg_k(const int* __restrict__ csr,
    const int* __restrict__ off, const int* __restrict__ et,
    const int* __restrict__ es, const float* __restrict__ alpha,
    const float* __restrict__ hr2, float* __restrict__ hout,
    unsigned short* __restrict__ hh, unsigned short* __restrict__ hl)
{
  int n = blockIdx.x;
  int o0 = off[n], o1 = off[n + 1];
  int ch = threadIdx.x;
  float acc = 0.f;
  for (int i = o0; i < o1; ++i) {
    int e = csr[i];
    acc += alpha[e] * hr2[(size_t)es[e] * (RR * D) + et[e] * D + ch];
  }
  float v = acc > 0.f ? acc : expm1f(acc);
  size_t idx = (size_t)n * D + ch;
  hout[idx] = v;
  unsigned short hb = f2bf(v);
  hh[idx] = hb;
  hl[idx] = f2bf(v - bf2f(hb));
}

// ---------------- final attention scores (fp32) ----------------
__global__ __launch_bounds__(256) void attn_k(const float* __restrict__ q,
    const float* __restrict__ kmat, float* __restrict__ out)
{
  __shared__ float Qs[64][36];
  __shared__ float Kst[32][68];
  int tid = threadIdx.x;
  int bh = blockIdx.y; int b = bh >> 3, h = bh & 7;
  int rb = (blockIdx.x >> 3) * 64, cb = (blockIdx.x & 7) * 64;
  int li = tid >> 2, ld = (tid & 3) * 8;

  const float* qp = q + ((size_t)(b * SS) + rb + li) * D + h * 32 + ld;
  const float* kp = kmat + ((size_t)(b * SS) + cb + li) * D + h * 32 + ld;
  float4 q0 = *(const float4*)qp, q1 = *(const float4*)(qp + 4);
  float4 k0 = *(const float4*)kp, k1 = *(const float4*)(kp + 4);
  *(float4*)&Qs[li][ld] = q0; *(float4*)&Qs[li][ld + 4] = q1;
  Kst[ld+0][li] = k0.x; Kst[ld+1][li] = k0.y; Kst[ld+2][li] = k0.z; Kst[ld+3][li] = k0.w;
  Kst[ld+4][li] = k1.x; Kst[ld+5][li] = k1.y; Kst[ld+6][li] = k1.z; Kst[ld+7][li] = k1.w;
  __syncthreads();

  int tr = tid >> 4, tc = tid & 15;
  float acc[4][4] = {};
#pragma unroll
  for (int d = 0; d < 32; ++d) {
    float a0 = Qs[tr][d], a1 = Qs[tr+16][d], a2 = Qs[tr+32][d], a3 = Qs[tr+48][d];
    float b0 = Kst[d][tc*4+0], b1 = Kst[d][tc*4+1], b2 = Kst[d][tc*4+2], b3 = Kst[d][tc*4+3];
    acc[0][0] += a0*b0; acc[0][1] += a0*b1; acc[0][2] += a0*b2; acc[0][3] += a0*b3;
    acc[1][0] += a1*b0; acc[1][1] += a1*b1; acc[1][2] += a1*b2; acc[1][3] += a1*b3;
    acc[2][0] += a2*b0; acc[2][1] += a2*b1; acc[2][2] += a2*b2; acc[2][3] += a2*b3;
    acc[3][0] += a3*b0; acc[3][1] += a3*b1; acc[3][2] += a3*b2; acc[3][3] += a3*b3;
  }
  const float scale = 0.17677669529663687f; // 1/sqrt(32)
  size_t ob = (size_t)bh * SS * SS;
#pragma unroll
  for (int u = 0; u < 4; ++u) {
    float4 v = make_float4(acc[u][0]*scale, acc[u][1]*scale, acc[u][2]*scale, acc[u][3]*scale);
    *(float4*)(out + ob + (size_t)(rb + tr + 16*u) * SS + cb + tc*4) = v;
  }
}

// ---------------- launcher ----------------
extern "C" void kernel_launch(void* const* d_in, const int* in_sizes, int n_in,
                              void* d_out, int out_size, void* d_ws, size_t ws_size,
                              hipStream_t stream) {
  const float* x    = (const float*)d_in[0];
  const int*   es   = (const int*)d_in[1];
  const int*   ed   = (const int*)d_in[2];
  const int*   et   = (const int*)d_in[3];
  const float* Wl   = (const float*)d_in[4];
  const float* bl   = (const float*)d_in[5];
  const float* Wgat = (const float*)d_in[6];
  const float* asr  = (const float*)d_in[7];
  const float* adt  = (const float*)d_in[8];
  const float* W1   = (const float*)d_in[9];
  const float* b1   = (const float*)d_in[10];
  const float* Wq   = (const float*)d_in[11];
  const float* bq   = (const float*)d_in[12];
  const float* Wk   = (const float*)d_in[13];
  const float* bk   = (const float*)d_in[14];
  float* out = (float*)d_out;

  char* w = (char*)d_ws;
  size_t o = 0;
  auto alloc = [&](size_t bytes) { void* p = w + o; o += (bytes + 255) & ~(size_t)255; return p; };
  float*          h     = (float*)alloc((size_t)NN * D * 4);
  unsigned short* hh    = (unsigned short*)alloc((size_t)NN * D * 2);
  unsigned short* hl    = (unsigned short*)alloc((size_t)NN * D * 2);
  unsigned short* Wgt_h = (unsigned short*)alloc((size_t)LL * RR * D * D * 2);
  unsigned short* Wgt_l = (unsigned short*)alloc((size_t)LL * RR * D * D * 2);
  unsigned short* wlh   = (unsigned short*)alloc((size_t)D * D * 2);
  unsigned short* wll   = (unsigned short*)alloc((size_t)D * D * 2);
  unsigned short* w1h   = (unsigned short*)alloc((size_t)D * D * 2);
  unsigned short* w1l   = (unsigned short*)alloc((size_t)D * D * 2);
  unsigned short* wqh   = (unsigned short*)alloc((size_t)D * D * 2);
  unsigned short* wql   = (unsigned short*)alloc((size_t)D * D * 2);
  unsigned short* wkh   = (unsigned short*)alloc((size_t)D * D * 2);
  unsigned short* wkl   = (unsigned short*)alloc((size_t)D * D * 2);
  float* wa    = (float*)alloc((size_t)RR * D * 4);
  float* ssrc  = (float*)alloc((size_t)RR * NN * 4);
  float* sdst  = (float*)alloc((size_t)RR * NN * 4);
  float* logit = (float*)alloc((size_t)EE * 4);
  float* alpha = (float*)alloc((size_t)EE * 4);
  float* mx    = (float*)alloc((size_t)NN * 4);
  float* dn    = (float*)alloc((size_t)NN * 4);
  int*   cnt   = (int*)alloc((size_t)NN * 4);
  int*   off   = (int*)alloc((size_t)(NN + 1) * 4);
  int*   cur   = (int*)alloc((size_t)NN * 4);
  int*   csr   = (int*)alloc((size_t)EE * 4);
  // 32 MB multipurpose region
  char* big = (char*)alloc((size_t)NN * RR * D * 4);
  float*          hr2 = (float*)big;                       // [NN][R*D] during layers
  unsigned short* xh  = (unsigned short*)big;              // before layers
  unsigned short* xl  = (unsigned short*)(big + (size_t)NN * D * 2);
  unsigned short* h1h = (unsigned short*)big;              // after layers
  unsigned short* h1l = (unsigned short*)(big + (size_t)NN * D * 2);
  float*          q   = (float*)(big + (size_t)NN * D * 4);
  float*          kb  = (float*)(big + (size_t)NN * D * 8);

  // CSR build
  hipMemsetAsync(cnt, 0, NN * sizeof(int), stream);
  count_k<<<EE / 256, 256, 0, stream>>>(ed, cnt);
  scan_k<<<1, 1024, 0, stream>>>(cnt, off, cur);
  fill_k<<<EE / 256, 256, 0, stream>>>(ed, cur, csr);

  // conversions
  cvt_split_k<<<NN * D / 1024, 256, 0, stream>>>(x, xh, xl, NN * D / 4);
  cvt_split_k<<<D * D / 1024, 256, 0, stream>>>(Wl, wlh, wll, D * D / 4);
  cvt_split_k<<<D * D / 1024, 256, 0, stream>>>(W1, w1h, w1l, D * D / 4);
  cvt_split_k<<<D * D / 1024, 256, 0, stream>>>(Wq, wqh, wql, D * D / 4);
  cvt_split_k<<<D * D / 1024, 256, 0, stream>>>(Wk, wkh, wkl, D * D / 4);
  transp_split_k<<<dim3(8, 8, LL * RR), 256, 0, stream>>>(Wgat, Wgt_h, Wgt_l);

  // h = x @ Wl^T + bl (fp32 + split)
  gemm_split<64, 64, true, true><<<dim3(4, 64), 256, 0, stream>>>(
      xh, xl, wlh, wll, bl, h, hh, hl, NN, D, D);

  for (int l = 0; l < LL; ++l) {
    wa_k<<<RR * D / 4, 256, 0, stream>>>(Wgat + (size_t)l * RR * D * D,
                                         asr + (size_t)l * RR * D, wa);
    // hr2[n, r*D+e] = h @ Wgat[l]  (fused over relations, N=2048)
    gemm_split<128, 128, true, false><<<dim3(16, 32), 256, 0, stream>>>(
        hh, hl, Wgt_h + (size_t)l * RR * D * D, Wgt_l + (size_t)l * RR * D * D,
        nullptr, hr2, nullptr, nullptr, NN, RR * D, D);
    scores2_k<<<NN, 256, 0, stream>>>(h, wa, adt + (size_t)l * RR * D, ssrc, sdst);
    edge_logits_k<<<EE / 256, 256, 0, stream>>>(et, es, ed, ssrc, sdst, logit);
    node_softmax_k<<<NN / 4, 256, 0, stream>>>(csr, off, logit, mx, dn);
    alpha_k<<<EE / 256, 256, 0, stream>>>(ed, logit, mx, dn, alpha);
    agg_k<<<NN, 256, 0, stream>>>(csr, off, et, es, alpha, hr2, h, hh, hl);
  }

  // h1 = h @ W1^T + b1 (split only); q/k fp32
  gemm_split<64, 64, false, true><<<dim3(4, 64), 256, 0, stream>>>(
      hh, hl, w1h, w1l, b1, nullptr, h1h, h1l, NN, D, D);
  gemm_split<64, 64, true, false><<<dim3(4, 64), 256, 0, stream>>>(
      h1h, h1l, wqh, wql, bq, q, nullptr, nullptr, NN, D, D);
  gemm_split<64, 64, true, false><<<dim3(4, 64), 256, 0, stream>>>(
      h1h, h1l, wkh, wkl, bk, kb, nullptr, nullptr, NN, D, D);

  attn_k<<<dim3(64, BB * HH), 256, 0, stream>>>(q, kb, out);
}

// Round 3
// 273.993 us; speedup vs baseline: 2.3106x; 1.4331x over previous
//
#include <hip/hip_runtime.h>
#include <math.h>

#define NN 4096      // nodes = B*S
#define D 256        // DIN == DOUT
#define RR 8
#define LL 4
#define EE 65536
#define BB 8
#define SS 512
#define HH 8

typedef short bf16x8 __attribute__((ext_vector_type(8)));
typedef float f32x4 __attribute__((ext_vector_type(4)));

__device__ __forceinline__ unsigned short f2bf(float f) {
  unsigned u = __float_as_uint(f);
  unsigned r = (u + 0x7fffu + ((u >> 16) & 1u)) >> 16;
  return (unsigned short)r;
}
__device__ __forceinline__ float bf2f(unsigned short s) {
  return __uint_as_float(((unsigned)s) << 16);
}

__device__ __forceinline__ void gload16(unsigned short* dst, const unsigned short* src) {
  __builtin_amdgcn_global_load_lds(
      (const __attribute__((address_space(1))) void*)src,
      (__attribute__((address_space(3))) void*)dst, 16, 0, 0);
}

// ---------------- split-bf16 MFMA GEMM ----------------
// C[M,N] = (Ah+Al)[M,K] * (Bh+Bl)[N,K]^T (+bias), fp32 accum.
// 3-term split: Ah*Bh + Al*Bh + Ah*Bl. 256 threads = 4 waves in 2x2 grid.
template<int BM, int BN, bool F32OUT, bool SPLITOUT>
__global__ __launch_bounds__(256) void gemm_split(
    const unsigned short* __restrict__ Ah, const unsigned short* __restrict__ Al,
    const unsigned short* __restrict__ Bh, const unsigned short* __restrict__ Bl,
    const float* __restrict__ bias,
    float* __restrict__ C, unsigned short* __restrict__ Ch, unsigned short* __restrict__ Cl,
    int M, int N, int K)
{
  constexpr int MF = BM / 32;   // 16x16 frags per wave (m)
  constexpr int NF = BN / 32;
  __shared__ unsigned short lds[2 * (BM + BN) * 32];
  unsigned short* lA = lds;                 // [Ah: BM*32][Al: BM*32]
  unsigned short* lB = lds + 2 * BM * 32;   // [Bh: BN*32][Bl: BN*32]

  const int t = threadIdx.x;
  const int lane = t & 63;
  const int w = t >> 6;
  const int wm = w >> 1, wn = w & 1;
  const int rb = blockIdx.y * BM;
  const int cb = blockIdx.x * BN;

  f32x4 acc[MF][NF];
#pragma unroll
  for (int m = 0; m < MF; ++m)
#pragma unroll
    for (int n = 0; n < NF; ++n)
      acc[m][n] = (f32x4){0.f, 0.f, 0.f, 0.f};

  const int srow = t >> 2, sslot = t & 3;
  const unsigned short* gAh = Ah + (size_t)(rb + srow) * K + sslot * 8;
  const unsigned short* gAl = Al + (size_t)(rb + srow) * K + sslot * 8;
  const unsigned short* gBh = Bh + (size_t)(cb + srow) * K + sslot * 8;
  const unsigned short* gBl = Bl + (size_t)(cb + srow) * K + sslot * 8;

  for (int k0 = 0; k0 < K; k0 += 32) {
#pragma unroll
    for (int i = 0; i < BM / 64; ++i) {
      gload16(lA + i * 2048 + t * 8,           gAh + (size_t)i * 64 * K + k0);
      gload16(lA + BM * 32 + i * 2048 + t * 8, gAl + (size_t)i * 64 * K + k0);
    }
#pragma unroll
    for (int i = 0; i < BN / 64; ++i) {
      gload16(lB + i * 2048 + t * 8,           gBh + (size_t)i * 64 * K + k0);
      gload16(lB + BN * 32 + i * 2048 + t * 8, gBl + (size_t)i * 64 * K + k0);
    }
    __syncthreads();

    bf16x8 ah[MF], al[MF];
#pragma unroll
    for (int m = 0; m < MF; ++m) {
      int off = (wm * (BM / 2) + m * 16 + (lane & 15)) * 32 + (lane >> 4) * 8;
      ah[m] = *(const bf16x8*)(lA + off);
      al[m] = *(const bf16x8*)(lA + BM * 32 + off);
    }
#pragma unroll
    for (int n = 0; n < NF; ++n) {
      int boff = (wn * (BN / 2) + n * 16 + (lane & 15)) * 32 + (lane >> 4) * 8;
      bf16x8 bh = *(const bf16x8*)(lB + boff);
      bf16x8 bl = *(const bf16x8*)(lB + BN * 32 + boff);
#pragma unroll
      for (int m = 0; m < MF; ++m) {
        acc[m][n] = __builtin_amdgcn_mfma_f32_16x16x32_bf16(ah[m], bh, acc[m][n], 0, 0, 0);
        acc[m][n] = __builtin_amdgcn_mfma_f32_16x16x32_bf16(al[m], bh, acc[m][n], 0, 0, 0);
        acc[m][n] = __builtin_amdgcn_mfma_f32_16x16x32_bf16(ah[m], bl, acc[m][n], 0, 0, 0);
      }
    }
    __syncthreads();
  }

#pragma unroll
  for (int m = 0; m < MF; ++m) {
#pragma unroll
    for (int n = 0; n < NF; ++n) {
      int row0 = rb + wm * (BM / 2) + m * 16 + (lane >> 4) * 4;
      int col = cb + wn * (BN / 2) + n * 16 + (lane & 15);
      float bv = bias ? bias[col] : 0.f;
#pragma unroll
      for (int j = 0; j < 4; ++j) {
        float v = acc[m][n][j] + bv;
        size_t idx = (size_t)(row0 + j) * N + col;
        if (F32OUT) C[idx] = v;
        if (SPLITOUT) {
          unsigned short hb = f2bf(v);
          Ch[idx] = hb;
          Cl[idx] = f2bf(v - bf2f(hb));
        }
      }
    }
  }
}

// ---------------- fp32 -> bf16 hi/lo split (x) ----------------
__global__ __launch_bounds__(256) void cvt_split_k(const float* __restrict__ src,
    unsigned short* __restrict__ hi, unsigned short* __restrict__ lo, int n4)
{
  int i = blockIdx.x * 256 + threadIdx.x;
  if (i >= n4) return;
  float4 v = ((const float4*)src)[i];
  ushort4 h, l;
  h.x = f2bf(v.x); l.x = f2bf(v.x - bf2f(h.x));
  h.y = f2bf(v.y); l.y = f2bf(v.y - bf2f(h.y));
  h.z = f2bf(v.z); l.z = f2bf(v.z - bf2f(h.z));
  h.w = f2bf(v.w); l.w = f2bf(v.w - bf2f(h.w));
  ((ushort4*)hi)[i] = h;
  ((ushort4*)lo)[i] = l;
}

// ---------------- 4 weight matrices (D x D) in one launch ----------------
__global__ __launch_bounds__(256) void cvt4_k(
    const float* __restrict__ s0, const float* __restrict__ s1,
    const float* __restrict__ s2, const float* __restrict__ s3,
    unsigned short* __restrict__ h0, unsigned short* __restrict__ h1,
    unsigned short* __restrict__ h2, unsigned short* __restrict__ h3,
    unsigned short* __restrict__ l0, unsigned short* __restrict__ l1,
    unsigned short* __restrict__ l2, unsigned short* __restrict__ l3)
{
  const float* src; unsigned short* hi; unsigned short* lo;
  switch (blockIdx.z) {
    case 0: src = s0; hi = h0; lo = l0; break;
    case 1: src = s1; hi = h1; lo = l1; break;
    case 2: src = s2; hi = h2; lo = l2; break;
    default: src = s3; hi = h3; lo = l3; break;
  }
  int i = blockIdx.x * 256 + threadIdx.x;   // D*D/4 = 16384 float4s
  float4 v = ((const float4*)src)[i];
  ushort4 h, l;
  h.x = f2bf(v.x); l.x = f2bf(v.x - bf2f(h.x));
  h.y = f2bf(v.y); l.y = f2bf(v.y - bf2f(h.y));
  h.z = f2bf(v.z); l.z = f2bf(v.z - bf2f(h.z));
  h.w = f2bf(v.w); l.w = f2bf(v.w - bf2f(h.w));
  ((ushort4*)hi)[i] = h;
  ((ushort4*)lo)[i] = l;
}

// ---------------- Wgat [G][D][D] -> transposed hi/lo [G][D][D] (e-major) ---------
__global__ __launch_bounds__(256) void transp_split_k(const float* __restrict__ W,
    unsigned short* __restrict__ th, unsigned short* __restrict__ tl)
{
  __shared__ float s[32][33];
  int g = blockIdx.z, bi = blockIdx.y, bj = blockIdx.x;
  int t = threadIdx.x;
  int r = t >> 3, c = (t & 7) * 4;
  float4 v = *(const float4*)(W + ((size_t)g * D + bi * 32 + r) * D + bj * 32 + c);
  s[r][c + 0] = v.x; s[r][c + 1] = v.y; s[r][c + 2] = v.z; s[r][c + 3] = v.w;
  __syncthreads();
  size_t ob = ((size_t)g * D + bj * 32 + r) * D + bi * 32 + c;
  ushort4 h, l;
  float o0 = s[c + 0][r], o1 = s[c + 1][r], o2 = s[c + 2][r], o3 = s[c + 3][r];
  h.x = f2bf(o0); l.x = f2bf(o0 - bf2f(h.x));
  h.y = f2bf(o1); l.y = f2bf(o1 - bf2f(h.y));
  h.z = f2bf(o2); l.z = f2bf(o2 - bf2f(h.z));
  h.w = f2bf(o3); l.w = f2bf(o3 - bf2f(h.w));
  *(ushort4*)(th + ob) = h;
  *(ushort4*)(tl + ob) = l;
}

// ---------------- CSR build ----------------
__global__ void count_k(const int* __restrict__ ed, int* __restrict__ cnt) {
  int e = blockIdx.x * 256 + threadIdx.x;
  if (e < EE) atomicAdd(&cnt[ed[e]], 1);
}

__global__ __launch_bounds__(1024) void scan_k(const int* __restrict__ cnt,
    int* __restrict__ off, int* __restrict__ cur) {
  __shared__ int part[1024];
  int t = threadIdx.x;
  int base = t * 4;
  int c0 = cnt[base], c1 = cnt[base+1], c2 = cnt[base+2], c3 = cnt[base+3];
  int s = c0 + c1 + c2 + c3;
  part[t] = s;
  __syncthreads();
  for (int o = 1; o < 1024; o <<= 1) {
    int v = 0;
    if (t >= o) v = part[t - o];
    __syncthreads();
    part[t] += v;
    __syncthreads();
  }
  int excl = part[t] - s;
  off[base] = excl; off[base+1] = excl + c0; off[base+2] = excl + c0 + c1;
  off[base+3] = excl + c0 + c1 + c2;
  cur[base] = excl; cur[base+1] = excl + c0; cur[base+2] = excl + c0 + c1;
  cur[base+3] = excl + c0 + c1 + c2;
  if (t == 1023) off[NN] = EE;
}

__global__ void fill_k(const int* __restrict__ ed, int* __restrict__ cur,
                       int* __restrict__ csr) {
  int e = blockIdx.x * 256 + threadIdx.x;
  if (e < EE) { int p = atomicAdd(&cur[ed[e]], 1); csr[p] = e; }
}

// ------- wa[l,r,d] = sum_e Wgat[l,r,d,e] * a_src[l,r,e]  (all layers) -------
__global__ __launch_bounds__(256) void wa_all_k(const float* __restrict__ Wg,
    const float* __restrict__ asrc, float* __restrict__ wa)
{
  int wid = blockIdx.x * 4 + (threadIdx.x >> 6);   // 0..LL*RR*D-1
  int lane = threadIdx.x & 63;
  int lr = wid >> 8, d = wid & 255;                // lr = l*RR + r
  const float* row = Wg + ((size_t)lr * D + d) * D;
  const float* av = asrc + (size_t)lr * D;
  float s = 0.f;
  for (int i = lane; i < D; i += 64) s += row[i] * av[i];
#pragma unroll
  for (int o = 32; o; o >>= 1) s += __shfl_down(s, o);
  if (lane == 0) wa[wid] = s;
}

// ---------------- layer-0 scores: ssrc[r,n]=h[n].wa[r], sdst[r,n]=h[n].adst[r] ----
__global__ __launch_bounds__(256) void scores2_k(const float* __restrict__ h,
    const float* __restrict__ wa, const float* __restrict__ adst,
    float* __restrict__ ssrc, float* __restrict__ sdst)
{
  int n = blockIdx.x;
  int w = threadIdx.x >> 6, lane = threadIdx.x & 63;
  float4 hv = ((const float4*)(h + (size_t)n * D))[lane];
#pragma unroll
  for (int rr = 0; rr < 2; ++rr) {
    int r = w * 2 + rr;
    float4 a = ((const float4*)(wa + (size_t)r * D))[lane];
    float4 b = ((const float4*)(adst + (size_t)r * D))[lane];
    float s1 = hv.x*a.x + hv.y*a.y + hv.z*a.z + hv.w*a.w;
    float s2 = hv.x*b.x + hv.y*b.y + hv.z*b.z + hv.w*b.w;
#pragma unroll
    for (int o = 32; o; o >>= 1) { s1 += __shfl_down(s1, o); s2 += __shfl_down(s2, o); }
    if (lane == 0) { ssrc[(size_t)r * NN + n] = s1; sdst[(size_t)r * NN + n] = s2; }
  }
}

// ------- fused per-node: edge logits + softmax max/denom (wave per node) -------
__global__ __launch_bounds__(256) void edge_softmax_k(const int* __restrict__ csr,
    const int* __restrict__ off, const int* __restrict__ et, const int* __restrict__ es,
    const float* __restrict__ ssrc, const float* __restrict__ sdst,
    float* __restrict__ logit, float* __restrict__ mx, float* __restrict__ dn)
{
  int wave = threadIdx.x >> 6, lane = threadIdx.x & 63;
  int n = blockIdx.x * 4 + wave;
  int o0 = off[n], o1 = off[n + 1];
  float m = -INFINITY;
  for (int i = o0 + lane; i < o1; i += 64) {
    int e = csr[i];
    int t = et[e];
    float v = ssrc[(size_t)t * NN + es[e]] + sdst[(size_t)t * NN + n];
    v = v > 0.f ? v : 0.2f * v;
    logit[e] = v;
    m = fmaxf(m, v);
  }
#pragma unroll
  for (int o = 32; o; o >>= 1) m = fmaxf(m, __shfl_xor(m, o));
  float s = 0.f;
  for (int i = o0 + lane; i < o1; i += 64) s += expf(logit[csr[i]] - m);
#pragma unroll
  for (int o = 32; o; o >>= 1) s += __shfl_xor(s, o);
  if (lane == 0) { mx[n] = m; dn[n] = s; }
}

// --- per-node aggregation + ELU -> bf16 hi/lo h; fused next-layer scores ---
__global__ __launch_bounds__(256) void agg_k(const int* __restrict__ csr,
    const int* __restrict__ off, const int* __restrict__ et,
    const int* __restrict__ es, const float* __restrict__ logit,
    const float* __restrict__ mx, const float* __restrict__ dn,
    const float* __restrict__ hr2,
    unsigned short* __restrict__ hh, unsigned short* __restrict__ hl,
    const float* __restrict__ wa_next, const float* __restrict__ adst_next,
    float* __restrict__ ssrc, float* __restrict__ sdst)
{
  __shared__ float shA[256];
  __shared__ int shOff[256];
  int n = blockIdx.x, ch = threadIdx.x;
  int o0 = off[n], o1 = off[n + 1];
  float m = mx[n], dinv = 1.f / (dn[n] + 1e-16f);
  float acc = 0.f;
  for (int base = o0; base < o1; base += 256) {
    int cnt = min(256, o1 - base);
    __syncthreads();
    if (ch < cnt) {
      int e = csr[base + ch];
      shA[ch] = expf(logit[e] - m) * dinv;
      shOff[ch] = es[e] * (RR * D) + et[e] * D;
    }
    __syncthreads();
    for (int i = 0; i < cnt; ++i)
      acc += shA[i] * hr2[(size_t)shOff[i] + ch];
  }
  float v = acc > 0.f ? acc : expm1f(acc);
  size_t idx = (size_t)n * D + ch;
  unsigned short hb = f2bf(v);
  hh[idx] = hb;
  hl[idx] = f2bf(v - bf2f(hb));

  if (wa_next) {   // fused scores for next layer
    __syncthreads();
    shA[ch] = v;
    __syncthreads();
    int wv = ch >> 6, lane = ch & 63;
#pragma unroll
    for (int rr = 0; rr < 2; ++rr) {
      int r = wv * 2 + rr;
      const float* wr = wa_next + (size_t)r * D;
      const float* ar = adst_next + (size_t)r * D;
      float s1 = shA[lane] * wr[lane] + shA[lane+64] * wr[lane+64]
               + shA[lane+128] * wr[lane+128] + shA[lane+192] * wr[lane+192];
      float s2 = shA[lane] * ar[lane] + shA[lane+64] * ar[lane+64]
               + shA[lane+128] * ar[lane+128] + shA[lane+192] * ar[lane+192];
#pragma unroll
      for (int o = 32; o; o >>= 1) { s1 += __shfl_down(s1, o); s2 += __shfl_down(s2, o); }
      if (lane == 0) { ssrc[(size_t)r * NN + n] = s1; sdst[(size_t)r * NN + n] = s2; }
    }
  }
}

// ---------------- final attention scores via split-bf16 MFMA ----------------
__global__ __launch_bounds__(256) void attn_mfma_k(
    const unsigned short* __restrict__ qh, const unsigned short* __restrict__ ql,
    const unsigned short* __restrict__ kh, const unsigned short* __restrict__ kl,
    float* __restrict__ out)
{
  int bh = blockIdx.y; int b = bh >> 3, hd = bh & 7;
  int rb = (blockIdx.x >> 3) * 64, cb = (blockIdx.x & 7) * 64;
  int t = threadIdx.x, lane = t & 63, w = t >> 6;
  int wm = w >> 1, wn = w & 1;
  int colk = hd * 32 + (lane >> 4) * 8;
  int arow = b * SS + rb + wm * 32 + (lane & 15);
  int brow = b * SS + cb + wn * 32 + (lane & 15);

  bf16x8 aH[2], aL[2], bH[2], bL[2];
#pragma unroll
  for (int m = 0; m < 2; ++m) {
    size_t o1 = (size_t)(arow + m * 16) * D + colk;
    aH[m] = *(const bf16x8*)(qh + o1);
    aL[m] = *(const bf16x8*)(ql + o1);
    size_t o2 = (size_t)(brow + m * 16) * D + colk;
    bH[m] = *(const bf16x8*)(kh + o2);
    bL[m] = *(const bf16x8*)(kl + o2);
  }
  f32x4 acc[2][2];
#pragma unroll
  for (int m = 0; m < 2; ++m)
#pragma unroll
    for (int n = 0; n < 2; ++n) {
      acc[m][n] = (f32x4){0.f, 0.f, 0.f, 0.f};
      acc[m][n] = __builtin_amdgcn_mfma_f32_16x16x32_bf16(aH[m], bH[n], acc[m][n], 0, 0, 0);
      acc[m][n] = __builtin_amdgcn_mfma_f32_16x16x32_bf16(aL[m], bH[n], acc[m][n], 0, 0, 0);
      acc[m][n] = __builtin_amdgcn_mfma_f32_16x16x32_bf16(aH[m], bL[n], acc[m][n], 0, 0, 0);
    }
  const float scale = 0.17677669529663687f; // 1/sqrt(32)
  size_t ob = (size_t)bh * SS * SS;
#pragma unroll
  for (int m = 0; m < 2; ++m)
#pragma unroll
    for (int n = 0; n < 2; ++n) {
      int row0 = rb + wm * 32 + m * 16 + (lane >> 4) * 4;
      int col = cb + wn * 32 + n * 16 + (lane & 15);
#pragma unroll
      for (int j = 0; j < 4; ++j)
        out[ob + (size_t)(row0 + j) * SS + col] = acc[m][n][j] * scale;
    }
}

// ---------------- launcher ----------------
extern "C" void kernel_launch(void* const* d_in, const int* in_sizes, int n_in,
                              void* d_out, int out_size, void* d_ws, size_t ws_size,
                              hipStream_t stream) {
  const float* x    = (const float*)d_in[0];
  const int*   es   = (const int*)d_in[1];
  const int*   ed   = (const int*)d_in[2];
  const int*   et   = (const int*)d_in[3];
  const float* Wl   = (const float*)d_in[4];
  const float* bl   = (const float*)d_in[5];
  const float* Wgat = (const float*)d_in[6];
  const float* asr  = (const float*)d_in[7];
  const float* adt  = (const float*)d_in[8];
  const float* W1   = (const float*)d_in[9];
  const float* b1   = (const float*)d_in[10];
  const float* Wq   = (const float*)d_in[11];
  const float* bq   = (const float*)d_in[12];
  const float* Wk   = (const float*)d_in[13];
  const float* bk   = (const float*)d_in[14];
  float* out = (float*)d_out;

  char* w = (char*)d_ws;
  size_t o = 0;
  auto alloc = [&](size_t bytes) { void* p = w + o; o += (bytes + 255) & ~(size_t)255; return p; };
  float*          h     = (float*)alloc((size_t)NN * D * 4);
  unsigned short* hh    = (unsigned short*)alloc((size_t)NN * D * 2);
  unsigned short* hl    = (unsigned short*)alloc((size_t)NN * D * 2);
  unsigned short* Wgt_h = (unsigned short*)alloc((size_t)LL * RR * D * D * 2);
  unsigned short* Wgt_l = (unsigned short*)alloc((size_t)LL * RR * D * D * 2);
  unsigned short* wlh   = (unsigned short*)alloc((size_t)D * D * 2);
  unsigned short* wll   = (unsigned short*)alloc((size_t)D * D * 2);
  unsigned short* w1h   = (unsigned short*)alloc((size_t)D * D * 2);
  unsigned short* w1l   = (unsigned short*)alloc((size_t)D * D * 2);
  unsigned short* wqh   = (unsigned short*)alloc((size_t)D * D * 2);
  unsigned short* wql   = (unsigned short*)alloc((size_t)D * D * 2);
  unsigned short* wkh   = (unsigned short*)alloc((size_t)D * D * 2);
  unsigned short* wkl   = (unsigned short*)alloc((size_t)D * D * 2);
  float* wa    = (float*)alloc((size_t)LL * RR * D * 4);
  float* ssrc  = (float*)alloc((size_t)RR * NN * 4);
  float* sdst  = (float*)alloc((size_t)RR * NN * 4);
  float* logit = (float*)alloc((size_t)EE * 4);
  float* mx    = (float*)alloc((size_t)NN * 4);
  float* dn    = (float*)alloc((size_t)NN * 4);
  int*   cnt   = (int*)alloc((size_t)NN * 4);
  int*   off   = (int*)alloc((size_t)(NN + 1) * 4);
  int*   cur   = (int*)alloc((size_t)NN * 4);
  int*   csr   = (int*)alloc((size_t)EE * 4);
  // 32 MB multipurpose region
  char* big = (char*)alloc((size_t)NN * RR * D * 4);
  float*          hr2 = (float*)big;                     // [NN][R*D] during layers
  unsigned short* xh  = (unsigned short*)big;            // before layers
  unsigned short* xl  = (unsigned short*)(big + (size_t)NN * D * 2);
  unsigned short* h1h = (unsigned short*)big;            // after layers
  unsigned short* h1l = (unsigned short*)(big + (size_t)NN * D * 2);
  unsigned short* qh  = (unsigned short*)(big + (size_t)NN * D * 4);
  unsigned short* ql  = (unsigned short*)(big + (size_t)NN * D * 6);
  unsigned short* kh  = (unsigned short*)(big + (size_t)NN * D * 8);
  unsigned short* kl  = (unsigned short*)(big + (size_t)NN * D * 10);

  // CSR build
  hipMemsetAsync(cnt, 0, NN * sizeof(int), stream);
  count_k<<<EE / 256, 256, 0, stream>>>(ed, cnt);
  scan_k<<<1, 1024, 0, stream>>>(cnt, off, cur);
  fill_k<<<EE / 256, 256, 0, stream>>>(ed, cur, csr);

  // conversions (x; 4 dense weights fused; Wgat transpose-split; all-layer wa)
  cvt_split_k<<<NN * D / 1024, 256, 0, stream>>>(x, xh, xl, NN * D / 4);
  cvt4_k<<<dim3(D * D / 1024, 1, 4), 256, 0, stream>>>(
      Wl, W1, Wq, Wk, wlh, w1h, wqh, wkh, wll, w1l, wql, wkl);
  transp_split_k<<<dim3(8, 8, LL * RR), 256, 0, stream>>>(Wgat, Wgt_h, Wgt_l);
  wa_all_k<<<LL * RR * D / 4, 256, 0, stream>>>(Wgat, asr, wa);

  // h = x @ Wl^T + bl (fp32 for layer-0 scores + split for GEMM)
  gemm_split<64, 64, true, true><<<dim3(4, 64), 256, 0, stream>>>(
      xh, xl, wlh, wll, bl, h, hh, hl, NN, D, D);
  scores2_k<<<NN, 256, 0, stream>>>(h, wa, adt, ssrc, sdst);

  for (int l = 0; l < LL; ++l) {
    // hr2[n, r*D+e] = h @ Wgat[l] (fused over relations, N=2048)
    gemm_split<128, 128, true, false><<<dim3(16, 32), 256, 0, stream>>>(
        hh, hl, Wgt_h + (size_t)l * RR * D * D, Wgt_l + (size_t)l * RR * D * D,
        nullptr, hr2, nullptr, nullptr, NN, RR * D, D);
    edge_softmax_k<<<NN / 4, 256, 0, stream>>>(csr, off, et, es, ssrc, sdst,
                                               logit, mx, dn);
    const float* wan = (l < LL - 1) ? wa + (size_t)(l + 1) * RR * D : nullptr;
    const float* adn = (l < LL - 1) ? adt + (size_t)(l + 1) * RR * D : nullptr;
    agg_k<<<NN, 256, 0, stream>>>(csr, off, et, es, logit, mx, dn, hr2,
                                  hh, hl, wan, adn, ssrc, sdst);
  }

  // h1 = h @ W1^T + b1 ; q = h1 @ Wq^T + bq ; k = h1 @ Wk^T + bk (all split-only)
  gemm_split<64, 64, false, true><<<dim3(4, 64), 256, 0, stream>>>(
      hh, hl, w1h, w1l, b1, nullptr, h1h, h1l, NN, D, D);
  gemm_split<64, 64, false, true><<<dim3(4, 64), 256, 0, stream>>>(
      h1h, h1l, wqh, wql, bq, nullptr, qh, ql, NN, D, D);
  gemm_split<64, 64, false, true><<<dim3(4, 64), 256, 0, stream>>>(
      h1h, h1l, wkh, wkl, bk, nullptr, kh, kl, NN, D, D);

  attn_mfma_k<<<dim3(64, BB * HH), 256, 0, stream>>>(qh, ql, kh, kl, out);
}

// Round 4
// 258.039 us; speedup vs baseline: 2.4535x; 1.0618x over previous
//
#include <hip/hip_runtime.h>
#include <math.h>

#define NN 4096      // nodes = B*S
#define D 256        // DIN == DOUT
#define RR 8
#define LL 4
#define EE 65536
#define BB 8
#define SS 512
#define HH 8

typedef short bf16x8 __attribute__((ext_vector_type(8)));
typedef float f32x4 __attribute__((ext_vector_type(4)));

__device__ __forceinline__ unsigned short f2bf(float f) {
  unsigned u = __float_as_uint(f);
  unsigned r = (u + 0x7fffu + ((u >> 16) & 1u)) >> 16;
  return (unsigned short)r;
}
__device__ __forceinline__ float bf2f(unsigned short s) {
  return __uint_as_float(((unsigned)s) << 16);
}

__device__ __forceinline__ void gload16(unsigned short* dst, const unsigned short* src) {
  __builtin_amdgcn_global_load_lds(
      (const __attribute__((address_space(1))) void*)src,
      (__attribute__((address_space(3))) void*)dst, 16, 0, 0);
}

// ---------------- split-bf16 MFMA GEMM ----------------
// C[M,N] = (Ah+Al)[M,K] * (Bh+Bl)[N,K]^T (+bias), fp32 accum.
// 3-term split: Ah*Bh + Al*Bh + Ah*Bl. 256 threads = 4 waves in 2x2 grid.
template<int BM, int BN, bool F32OUT, bool SPLITOUT>
__global__ __launch_bounds__(256) void gemm_split(
    const unsigned short* __restrict__ Ah, const unsigned short* __restrict__ Al,
    const unsigned short* __restrict__ Bh, const unsigned short* __restrict__ Bl,
    const float* __restrict__ bias,
    float* __restrict__ C, unsigned short* __restrict__ Ch, unsigned short* __restrict__ Cl,
    int M, int N, int K)
{
  constexpr int MF = BM / 32;   // 16x16 frags per wave (m)
  constexpr int NF = BN / 32;
  __shared__ unsigned short lds[2 * (BM + BN) * 32];
  unsigned short* lA = lds;                 // [Ah: BM*32][Al: BM*32]
  unsigned short* lB = lds + 2 * BM * 32;   // [Bh: BN*32][Bl: BN*32]

  const int t = threadIdx.x;
  const int lane = t & 63;
  const int w = t >> 6;
  const int wm = w >> 1, wn = w & 1;
  const int rb = blockIdx.y * BM;
  const int cb = blockIdx.x * BN;

  f32x4 acc[MF][NF];
#pragma unroll
  for (int m = 0; m < MF; ++m)
#pragma unroll
    for (int n = 0; n < NF; ++n)
      acc[m][n] = (f32x4){0.f, 0.f, 0.f, 0.f};

  const int srow = t >> 2, sslot = t & 3;
  const unsigned short* gAh = Ah + (size_t)(rb + srow) * K + sslot * 8;
  const unsigned short* gAl = Al + (size_t)(rb + srow) * K + sslot * 8;
  const unsigned short* gBh = Bh + (size_t)(cb + srow) * K + sslot * 8;
  const unsigned short* gBl = Bl + (size_t)(cb + srow) * K + sslot * 8;

  for (int k0 = 0; k0 < K; k0 += 32) {
#pragma unroll
    for (int i = 0; i < BM / 64; ++i) {
      gload16(lA + i * 2048 + t * 8,           gAh + (size_t)i * 64 * K + k0);
      gload16(lA + BM * 32 + i * 2048 + t * 8, gAl + (size_t)i * 64 * K + k0);
    }
#pragma unroll
    for (int i = 0; i < BN / 64; ++i) {
      gload16(lB + i * 2048 + t * 8,           gBh + (size_t)i * 64 * K + k0);
      gload16(lB + BN * 32 + i * 2048 + t * 8, gBl + (size_t)i * 64 * K + k0);
    }
    __syncthreads();

    bf16x8 ah[MF], al[MF];
#pragma unroll
    for (int m = 0; m < MF; ++m) {
      int off = (wm * (BM / 2) + m * 16 + (lane & 15)) * 32 + (lane >> 4) * 8;
      ah[m] = *(const bf16x8*)(lA + off);
      al[m] = *(const bf16x8*)(lA + BM * 32 + off);
    }
#pragma unroll
    for (int n = 0; n < NF; ++n) {
      int boff = (wn * (BN / 2) + n * 16 + (lane & 15)) * 32 + (lane >> 4) * 8;
      bf16x8 bh = *(const bf16x8*)(lB + boff);
      bf16x8 bl = *(const bf16x8*)(lB + BN * 32 + boff);
#pragma unroll
      for (int m = 0; m < MF; ++m) {
        acc[m][n] = __builtin_amdgcn_mfma_f32_16x16x32_bf16(ah[m], bh, acc[m][n], 0, 0, 0);
        acc[m][n] = __builtin_amdgcn_mfma_f32_16x16x32_bf16(al[m], bh, acc[m][n], 0, 0, 0);
        acc[m][n] = __builtin_amdgcn_mfma_f32_16x16x32_bf16(ah[m], bl, acc[m][n], 0, 0, 0);
      }
    }
    __syncthreads();
  }

#pragma unroll
  for (int m = 0; m < MF; ++m) {
#pragma unroll
    for (int n = 0; n < NF; ++n) {
      int row0 = rb + wm * (BM / 2) + m * 16 + (lane >> 4) * 4;
      int col = cb + wn * (BN / 2) + n * 16 + (lane & 15);
      float bv = bias ? bias[col] : 0.f;
#pragma unroll
      for (int j = 0; j < 4; ++j) {
        float v = acc[m][n][j] + bv;
        size_t idx = (size_t)(row0 + j) * N + col;
        if (F32OUT) C[idx] = v;
        if (SPLITOUT) {
          unsigned short hb = f2bf(v);
          Ch[idx] = hb;
          Cl[idx] = f2bf(v - bf2f(hb));
        }
      }
    }
  }
}

// ---------------- fp32 -> bf16 hi/lo split ----------------
__global__ __launch_bounds__(256) void cvt_split_k(const float* __restrict__ src,
    unsigned short* __restrict__ hi, unsigned short* __restrict__ lo, int n4)
{
  int i = blockIdx.x * 256 + threadIdx.x;
  if (i >= n4) return;
  float4 v = ((const float4*)src)[i];
  ushort4 h, l;
  h.x = f2bf(v.x); l.x = f2bf(v.x - bf2f(h.x));
  h.y = f2bf(v.y); l.y = f2bf(v.y - bf2f(h.y));
  h.z = f2bf(v.z); l.z = f2bf(v.z - bf2f(h.z));
  h.w = f2bf(v.w); l.w = f2bf(v.w - bf2f(h.w));
  ((ushort4*)hi)[i] = h;
  ((ushort4*)lo)[i] = l;
}

// ---------------- Wgat [G][D][D] -> transposed hi/lo [G][D][D] (e-major) ---------
__global__ __launch_bounds__(256) void transp_split_k(const float* __restrict__ W,
    unsigned short* __restrict__ th, unsigned short* __restrict__ tl)
{
  __shared__ float s[32][33];
  int g = blockIdx.z, bi = blockIdx.y, bj = blockIdx.x;
  int t = threadIdx.x;
  int r = t >> 3, c = (t & 7) * 4;
  float4 v = *(const float4*)(W + ((size_t)g * D + bi * 32 + r) * D + bj * 32 + c);
  s[r][c + 0] = v.x; s[r][c + 1] = v.y; s[r][c + 2] = v.z; s[r][c + 3] = v.w;
  __syncthreads();
  size_t ob = ((size_t)g * D + bj * 32 + r) * D + bi * 32 + c;
  ushort4 h, l;
  float o0 = s[c + 0][r], o1 = s[c + 1][r], o2 = s[c + 2][r], o3 = s[c + 3][r];
  h.x = f2bf(o0); l.x = f2bf(o0 - bf2f(h.x));
  h.y = f2bf(o1); l.y = f2bf(o1 - bf2f(h.y));
  h.z = f2bf(o2); l.z = f2bf(o2 - bf2f(h.z));
  h.w = f2bf(o3); l.w = f2bf(o3 - bf2f(h.w));
  *(ushort4*)(th + ob) = h;
  *(ushort4*)(tl + ob) = l;
}

// ---------------- CSR build ----------------
__global__ void count_k(const int* __restrict__ ed, int* __restrict__ cnt) {
  int e = blockIdx.x * 256 + threadIdx.x;
  if (e < EE) atomicAdd(&cnt[ed[e]], 1);
}

__global__ __launch_bounds__(1024) void scan_k(const int* __restrict__ cnt,
    int* __restrict__ off, int* __restrict__ cur) {
  __shared__ int part[1024];
  int t = threadIdx.x;
  int base = t * 4;
  int c0 = cnt[base], c1 = cnt[base+1], c2 = cnt[base+2], c3 = cnt[base+3];
  int s = c0 + c1 + c2 + c3;
  part[t] = s;
  __syncthreads();
  for (int o = 1; o < 1024; o <<= 1) {
    int v = 0;
    if (t >= o) v = part[t - o];
    __syncthreads();
    part[t] += v;
    __syncthreads();
  }
  int excl = part[t] - s;
  off[base] = excl; off[base+1] = excl + c0; off[base+2] = excl + c0 + c1;
  off[base+3] = excl + c0 + c1 + c2;
  cur[base] = excl; cur[base+1] = excl + c0; cur[base+2] = excl + c0 + c1;
  cur[base+3] = excl + c0 + c1 + c2;
  if (t == 1023) off[NN] = EE;
}

__global__ void fill_k(const int* __restrict__ ed, int* __restrict__ cur,
                       int* __restrict__ csr) {
  int e = blockIdx.x * 256 + threadIdx.x;
  if (e < EE) { int p = atomicAdd(&cur[ed[e]], 1); csr[p] = e; }
}

// ------- wa[l,r,d] = sum_e Wgat[l,r,d,e] * a_src[l,r,e]  (all layers) -------
__global__ __launch_bounds__(256) void wa_all_k(const float* __restrict__ Wg,
    const float* __restrict__ asrc, float* __restrict__ wa)
{
  int wid = blockIdx.x * 4 + (threadIdx.x >> 6);   // 0..LL*RR*D-1
  int lane = threadIdx.x & 63;
  int lr = wid >> 8, d = wid & 255;                // lr = l*RR + r
  const float* row = Wg + ((size_t)lr * D + d) * D;
  const float* av = asrc + (size_t)lr * D;
  float s = 0.f;
  for (int i = lane; i < D; i += 64) s += row[i] * av[i];
#pragma unroll
  for (int o = 32; o; o >>= 1) s += __shfl_down(s, o);
  if (lane == 0) wa[wid] = s;
}

// ------- fold: wqk1[i][k] = sum_j Wsel[i][j] * W1[j][k]  (i<256: Wq, else Wk) ----
__global__ __launch_bounds__(256) void fold_k(const float* __restrict__ Wq,
    const float* __restrict__ Wk, const float* __restrict__ W1,
    unsigned short* __restrict__ fh, unsigned short* __restrict__ fl)
{
  int j = (blockIdx.x & 3) * 64 + (threadIdx.x & 63);   // output k index 0..255
  int i = (blockIdx.x >> 2) * 4 + (threadIdx.x >> 6);   // output row 0..511
  const float* row = i < 256 ? Wq + (size_t)i * D : Wk + (size_t)(i - 256) * D;
  float s = 0.f;
  for (int k = 0; k < D; ++k) s += row[k] * W1[(size_t)k * D + j];
  size_t idx = (size_t)i * D + j;
  unsigned short hb = f2bf(s);
  fh[idx] = hb;
  fl[idx] = f2bf(s - bf2f(hb));
}

// ------- fold bias: bqk[i] = Wsel[i] . b1 + bsel[i] ----------------
__global__ __launch_bounds__(256) void foldb_k(const float* __restrict__ Wq,
    const float* __restrict__ Wk, const float* __restrict__ b1,
    const float* __restrict__ bq, const float* __restrict__ bk,
    float* __restrict__ bqk)
{
  int idx = blockIdx.x * 4 + (threadIdx.x >> 6);  // 0..511
  int lane = threadIdx.x & 63;
  const float* row = idx < 256 ? Wq + (size_t)idx * D : Wk + (size_t)(idx - 256) * D;
  float s = 0.f;
  for (int i = lane; i < D; i += 64) s += row[i] * b1[i];
#pragma unroll
  for (int o = 32; o; o >>= 1) s += __shfl_down(s, o);
  if (lane == 0) bqk[idx] = s + (idx < 256 ? bq[idx] : bk[idx - 256]);
}

// ---------------- layer-0 scores: ssrc[r,n]=h[n].wa[r], sdst[r,n]=h[n].adst[r] ----
__global__ __launch_bounds__(256) void scores2_k(const float* __restrict__ h,
    const float* __restrict__ wa, const float* __restrict__ adst,
    float* __restrict__ ssrc, float* __restrict__ sdst)
{
  int n = blockIdx.x;
  int w = threadIdx.x >> 6, lane = threadIdx.x & 63;
  float4 hv = ((const float4*)(h + (size_t)n * D))[lane];
#pragma unroll
  for (int rr = 0; rr < 2; ++rr) {
    int r = w * 2 + rr;
    float4 a = ((const float4*)(wa + (size_t)r * D))[lane];
    float4 b = ((const float4*)(adst + (size_t)r * D))[lane];
    float s1 = hv.x*a.x + hv.y*a.y + hv.z*a.z + hv.w*a.w;
    float s2 = hv.x*b.x + hv.y*b.y + hv.z*b.z + hv.w*b.w;
#pragma unroll
    for (int o = 32; o; o >>= 1) { s1 += __shfl_down(s1, o); s2 += __shfl_down(s2, o); }
    if (lane == 0) { ssrc[(size_t)r * NN + n] = s1; sdst[(size_t)r * NN + n] = s2; }
  }
}

// ---- fully fused per-node: logits + softmax + aggregate + ELU + split +
// ---- next-layer scores. One block (256 thr) per node. deg <= 1024 assumed
// ---- (E/N = 16 uniform-random; max observed degree ~45).
__global__ __launch_bounds__(256) void agg_fused_k(
    const int* __restrict__ csr, const int* __restrict__ off,
    const int* __restrict__ et, const int* __restrict__ es,
    const float* __restrict__ ssrc, const float* __restrict__ sdst,
    const float* __restrict__ hr2,
    unsigned short* __restrict__ hh, unsigned short* __restrict__ hl,
    const float* __restrict__ wa_next, const float* __restrict__ adst_next,
    float* __restrict__ ssrc_o, float* __restrict__ sdst_o)
{
  __shared__ float slog[1024];
  __shared__ int soff[1024];
  __shared__ float sdn[RR];
  __shared__ float red[8];
  int n = blockIdx.x, tid = threadIdx.x;
  int o0 = off[n];
  int deg = off[n + 1] - o0;
  if (deg > 1024) deg = 1024;
  if (tid < RR) sdn[tid] = sdst[(size_t)tid * NN + n];
  __syncthreads();
  // logits (leaky relu) into LDS
  for (int i = tid; i < deg; i += 256) {
    int e = csr[o0 + i];
    int t = et[e], s = es[e];
    float v = ssrc[(size_t)t * NN + s] + sdn[t];
    slog[i] = v > 0.f ? v : 0.2f * v;
    soff[i] = s * (RR * D) + t * D;
  }
  __syncthreads();
  int lane = tid & 63, wv = tid >> 6;
  // block max
  float lm = -INFINITY;
  for (int i = tid; i < deg; i += 256) lm = fmaxf(lm, slog[i]);
#pragma unroll
  for (int o = 32; o; o >>= 1) lm = fmaxf(lm, __shfl_xor(lm, o));
  if (lane == 0) red[wv] = lm;
  __syncthreads();
  float m = fmaxf(fmaxf(red[0], red[1]), fmaxf(red[2], red[3]));
  // exp + block sum (each slog element owned by thread (i mod 256))
  float ls = 0.f;
  for (int i = tid; i < deg; i += 256) {
    float a = expf(slog[i] - m);
    slog[i] = a;
    ls += a;
  }
#pragma unroll
  for (int o = 32; o; o >>= 1) ls += __shfl_xor(ls, o);
  if (lane == 0) red[4 + wv] = ls;
  __syncthreads();
  float dinv = 1.f / (red[4] + red[5] + red[6] + red[7] + 1e-16f);
  // aggregation: thread = channel
  float acc = 0.f;
  for (int i = 0; i < deg; ++i)
    acc += slog[i] * hr2[(size_t)soff[i] + tid];
  acc *= dinv;
  float v = acc > 0.f ? acc : expm1f(acc);
  size_t idx = (size_t)n * D + tid;
  unsigned short hb = f2bf(v);
  hh[idx] = hb;
  hl[idx] = f2bf(v - bf2f(hb));

  if (wa_next) {   // fused scores for next layer (into ping-pong buffers)
    __syncthreads();
    slog[tid] = v;
    __syncthreads();
#pragma unroll
    for (int rr2 = 0; rr2 < 2; ++rr2) {
      int r = wv * 2 + rr2;
      const float* wr = wa_next + (size_t)r * D;
      const float* ar = adst_next + (size_t)r * D;
      float s1 = slog[lane] * wr[lane] + slog[lane+64] * wr[lane+64]
               + slog[lane+128] * wr[lane+128] + slog[lane+192] * wr[lane+192];
      float s2 = slog[lane] * ar[lane] + slog[lane+64] * ar[lane+64]
               + slog[lane+128] * ar[lane+128] + slog[lane+192] * ar[lane+192];
#pragma unroll
      for (int o = 32; o; o >>= 1) { s1 += __shfl_down(s1, o); s2 += __shfl_down(s2, o); }
      if (lane == 0) { ssrc_o[(size_t)r * NN + n] = s1; sdst_o[(size_t)r * NN + n] = s2; }
    }
  }
}

// ---------------- final attention scores via split-bf16 MFMA ----------------
// qk layout: [NN][512] hi/lo; q = cols [0,256), k = cols [256,512)
__global__ __launch_bounds__(256) void attn_mfma_k(
    const unsigned short* __restrict__ qkh, const unsigned short* __restrict__ qkl,
    float* __restrict__ out)
{
  int bh = blockIdx.y; int b = bh >> 3, hd = bh & 7;
  int rb = (blockIdx.x >> 3) * 64, cb = (blockIdx.x & 7) * 64;
  int t = threadIdx.x, lane = t & 63, w = t >> 6;
  int wm = w >> 1, wn = w & 1;
  int colq = hd * 32 + (lane >> 4) * 8;
  int colk = 256 + colq;
  int arow = b * SS + rb + wm * 32 + (lane & 15);
  int brow = b * SS + cb + wn * 32 + (lane & 15);

  bf16x8 aH[2], aL[2], bH[2], bL[2];
#pragma unroll
  for (int m = 0; m < 2; ++m) {
    size_t o1 = (size_t)(arow + m * 16) * 512 + colq;
    aH[m] = *(const bf16x8*)(qkh + o1);
    aL[m] = *(const bf16x8*)(qkl + o1);
    size_t o2 = (size_t)(brow + m * 16) * 512 + colk;
    bH[m] = *(const bf16x8*)(qkh + o2);
    bL[m] = *(const bf16x8*)(qkl + o2);
  }
  f32x4 acc[2][2];
#pragma unroll
  for (int m = 0; m < 2; ++m)
#pragma unroll
    for (int n = 0; n < 2; ++n) {
      acc[m][n] = (f32x4){0.f, 0.f, 0.f, 0.f};
      acc[m][n] = __builtin_amdgcn_mfma_f32_16x16x32_bf16(aH[m], bH[n], acc[m][n], 0, 0, 0);
      acc[m][n] = __builtin_amdgcn_mfma_f32_16x16x32_bf16(aL[m], bH[n], acc[m][n], 0, 0, 0);
      acc[m][n] = __builtin_amdgcn_mfma_f32_16x16x32_bf16(aH[m], bL[n], acc[m][n], 0, 0, 0);
    }
  const float scale = 0.17677669529663687f; // 1/sqrt(32)
  size_t ob = (size_t)bh * SS * SS;
#pragma unroll
  for (int m = 0; m < 2; ++m)
#pragma unroll
    for (int n = 0; n < 2; ++n) {
      int row0 = rb + wm * 32 + m * 16 + (lane >> 4) * 4;
      int col = cb + wn * 32 + n * 16 + (lane & 15);
#pragma unroll
      for (int j = 0; j < 4; ++j)
        out[ob + (size_t)(row0 + j) * SS + col] = acc[m][n][j] * scale;
    }
}

// ---------------- launcher ----------------
extern "C" void kernel_launch(void* const* d_in, const int* in_sizes, int n_in,
                              void* d_out, int out_size, void* d_ws, size_t ws_size,
                              hipStream_t stream) {
  const float* x    = (const float*)d_in[0];
  const int*   es   = (const int*)d_in[1];
  const int*   ed   = (const int*)d_in[2];
  const int*   et   = (const int*)d_in[3];
  const float* Wl   = (const float*)d_in[4];
  const float* bl   = (const float*)d_in[5];
  const float* Wgat = (const float*)d_in[6];
  const float* asr  = (const float*)d_in[7];
  const float* adt  = (const float*)d_in[8];
  const float* W1   = (const float*)d_in[9];
  const float* b1   = (const float*)d_in[10];
  const float* Wq   = (const float*)d_in[11];
  const float* bq   = (const float*)d_in[12];
  const float* Wk   = (const float*)d_in[13];
  const float* bk   = (const float*)d_in[14];
  float* out = (float*)d_out;

  char* w = (char*)d_ws;
  size_t o = 0;
  auto alloc = [&](size_t bytes) { void* p = w + o; o += (bytes + 255) & ~(size_t)255; return p; };
  float*          h     = (float*)alloc((size_t)NN * D * 4);
  unsigned short* hh    = (unsigned short*)alloc((size_t)NN * D * 2);
  unsigned short* hl    = (unsigned short*)alloc((size_t)NN * D * 2);
  unsigned short* Wgt_h = (unsigned short*)alloc((size_t)LL * RR * D * D * 2);
  unsigned short* Wgt_l = (unsigned short*)alloc((size_t)LL * RR * D * D * 2);
  unsigned short* wlh   = (unsigned short*)alloc((size_t)D * D * 2);
  unsigned short* wll   = (unsigned short*)alloc((size_t)D * D * 2);
  unsigned short* fqkh  = (unsigned short*)alloc((size_t)2 * D * D * 2);   // folded [512][256]
  unsigned short* fqkl  = (unsigned short*)alloc((size_t)2 * D * D * 2);
  float* bqk   = (float*)alloc((size_t)2 * D * 4);
  float* wa    = (float*)alloc((size_t)LL * RR * D * 4);
  float* ssrcA = (float*)alloc((size_t)RR * NN * 4);
  float* sdstA = (float*)alloc((size_t)RR * NN * 4);
  float* ssrcB = (float*)alloc((size_t)RR * NN * 4);
  float* sdstB = (float*)alloc((size_t)RR * NN * 4);
  int*   cnt   = (int*)alloc((size_t)NN * 4);
  int*   off   = (int*)alloc((size_t)(NN + 1) * 4);
  int*   cur   = (int*)alloc((size_t)NN * 4);
  int*   csr   = (int*)alloc((size_t)EE * 4);
  // 32 MB multipurpose region
  char* big = (char*)alloc((size_t)NN * RR * D * 4);
  float*          hr2 = (float*)big;                     // [NN][R*D] during layers
  unsigned short* xh  = (unsigned short*)big;            // before layers
  unsigned short* xl  = (unsigned short*)(big + (size_t)NN * D * 2);
  unsigned short* qkh = (unsigned short*)big;            // after layers [NN][512]
  unsigned short* qkl = (unsigned short*)(big + (size_t)NN * 512 * 2);

  // CSR build
  hipMemsetAsync(cnt, 0, NN * sizeof(int), stream);
  count_k<<<EE / 256, 256, 0, stream>>>(ed, cnt);
  scan_k<<<1, 1024, 0, stream>>>(cnt, off, cur);
  fill_k<<<EE / 256, 256, 0, stream>>>(ed, cur, csr);

  // conversions + precomputation
  cvt_split_k<<<NN * D / 1024, 256, 0, stream>>>(x, xh, xl, NN * D / 4);
  cvt_split_k<<<D * D / 1024, 256, 0, stream>>>(Wl, wlh, wll, D * D / 4);
  transp_split_k<<<dim3(8, 8, LL * RR), 256, 0, stream>>>(Wgat, Wgt_h, Wgt_l);
  wa_all_k<<<LL * RR * D / 4, 256, 0, stream>>>(Wgat, asr, wa);
  fold_k<<<512, 256, 0, stream>>>(Wq, Wk, W1, fqkh, fqkl);
  foldb_k<<<128, 256, 0, stream>>>(Wq, Wk, b1, bq, bk, bqk);

  // h = x @ Wl^T + bl (fp32 for layer-0 scores + split for GEMM)
  gemm_split<64, 64, true, true><<<dim3(4, 64), 256, 0, stream>>>(
      xh, xl, wlh, wll, bl, h, hh, hl, NN, D, D);
  scores2_k<<<NN, 256, 0, stream>>>(h, wa, adt, ssrcA, sdstA);

  for (int l = 0; l < LL; ++l) {
    // hr2[n, r*D+e] = h @ Wgat[l] (fused over relations, N=2048)
    gemm_split<128, 128, true, false><<<dim3(16, 32), 256, 0, stream>>>(
        hh, hl, Wgt_h + (size_t)l * RR * D * D, Wgt_l + (size_t)l * RR * D * D,
        nullptr, hr2, nullptr, nullptr, NN, RR * D, D);
    const float* wan = (l < LL - 1) ? wa + (size_t)(l + 1) * RR * D : nullptr;
    const float* adn = (l < LL - 1) ? adt + (size_t)(l + 1) * RR * D : nullptr;
    const float* sin_ = (l & 1) ? ssrcB : ssrcA;
    const float* din_ = (l & 1) ? sdstB : sdstA;
    float* sou_ = (l & 1) ? ssrcA : ssrcB;
    float* dou_ = (l & 1) ? sdstA : sdstB;
    agg_fused_k<<<NN, 256, 0, stream>>>(csr, off, et, es, sin_, din_, hr2,
                                        hh, hl, wan, adn, sou_, dou_);
  }

  // [q|k] = h @ (W{q,k}·W1)^T + (W{q,k}·b1 + b{q,k})   — one GEMM, N=512
  gemm_split<64, 64, false, true><<<dim3(8, 64), 256, 0, stream>>>(
      hh, hl, fqkh, fqkl, bqk, nullptr, qkh, qkl, NN, 512, D);

  attn_mfma_k<<<dim3(64, BB * HH), 256, 0, stream>>>(qkh, qkl, out);
}